// Round 6
// baseline (113.588 us; speedup 1.0000x reference)
//
#include <hip/hip_runtime.h>
#include <math.h>

// ---------------------------------------------------------------------------
// SINGLE-kernel Refiner. 112 blocks x 1024 threads, no workspace, no barrier.
//
// Algebra: feature channels enter each stage linearly through bilinear
// resize -> pre-reduce B[s][t][u][v] = sum_c conv_w[1+c][t]*f14[s][c][u][v];
// each stage's feature term is one bilinear sample of B. BN is affine =>
// commutes with upsample, so h-upsample fuses into the consumer.
//
// R6: each block recomputes its OWN cone's B rows via MFMA (bf16 inputs,
// fp32 accum): [<=280 px x 768] x [768 x 9] GEMM = 1 m-tile/wave, 24 K-steps.
// This removes kernel A and one ~5us graph-node overhead. B-fragments
// (conv_w in MFMA B-layout) are packed once into LDS and read as b128.
// Final Linear uses per-block LDS chunk-transpose of W (coalesced reads).
// LDS phases overlap via union: cbf (MFMA B-frags) -> y1/y2/y3 -> W chunk.
// ---------------------------------------------------------------------------

#define BN_EPS 1e-5f

typedef __attribute__((ext_vector_type(8))) short bf16x8;
typedef __attribute__((ext_vector_type(4))) float f32x4;

__device__ __forceinline__ float clampf(float x, float lo, float hi) {
    return fminf(fmaxf(x, lo), hi);
}

// f32 -> bf16 round-to-nearest-even
__device__ __forceinline__ unsigned short f2bf(float f) {
    unsigned u = __float_as_uint(f);
    return (unsigned short)((u + 0x7FFFu + ((u >> 16) & 1u)) >> 16);
}

__device__ __forceinline__ float sampleB(const float* __restrict__ Bt, float fy, float fx) {
    int y0 = (int)fy; float by = fy - (float)y0; int y1 = min(y0 + 1, 13);
    int x0 = (int)fx; float bx = fx - (float)x0; int x1 = min(x0 + 1, 13);
    return (1.f - by) * ((1.f - bx) * Bt[y0 * 14 + x0] + bx * Bt[y0 * 14 + x1])
         + by         * ((1.f - bx) * Bt[y1 * 14 + x0] + bx * Bt[y1 * 14 + x1]);
}

// Conv accumulator (pre-ReLU/BN) for one pixel at resolution H (h upsampled 2x).
__device__ __forceinline__ float stage_pixel(int i, int j, int H,
                                             const float* __restrict__ hsrc, int srcH,
                                             const float* __restrict__ sB,
                                             const float* __restrict__ cw, float bias) {
    float featScale = 14.0f / (float)H;
    float srcMax = (float)(srcH - 1);
    float acc = bias;
#pragma unroll
    for (int a = 0; a < 3; ++a) {
        int p = i + a - 1;
        if (p < 0 || p >= H) continue;          // SAME zero padding
        float fy = clampf(((float)p + 0.5f) * featScale - 0.5f, 0.f, 13.f);
        float hy = clampf(((float)p + 0.5f) * 0.5f - 0.5f, 0.f, srcMax);
        int hy0 = (int)hy; float fhy = hy - (float)hy0; int hy1 = min(hy0 + 1, srcH - 1);
#pragma unroll
        for (int bq = 0; bq < 3; ++bq) {
            int q = j + bq - 1;
            if (q < 0 || q >= H) continue;
            int t = a * 3 + bq;
            float fx = clampf(((float)q + 0.5f) * featScale - 0.5f, 0.f, 13.f);
            float bv = sampleB(sB + t * 196, fy, fx);
            float hx = clampf(((float)q + 0.5f) * 0.5f - 0.5f, 0.f, srcMax);
            int hx0 = (int)hx; float fhx = hx - (float)hx0; int hx1 = min(hx0 + 1, srcH - 1);
            float hval = (1.f - fhy) * ((1.f - fhx) * hsrc[hy0 * srcH + hx0] + fhx * hsrc[hy0 * srcH + hx1])
                       + fhy         * ((1.f - fhx) * hsrc[hy1 * srcH + hx0] + fhx * hsrc[hy1 * srcH + hx1]);
            acc += cw[t] * hval + bv;
        }
    }
    return acc;
}

// src rows needed for dst rows [dlo,dhi] of a stage at H=2*srcH.
__device__ __forceinline__ void srcRange(int dlo, int dhi, int srcH, int& slo, int& shi) {
    int H = 2 * srcH;
    int p0 = max(dlo - 1, 0), p1 = min(dhi + 1, H - 1);
    float h0 = fmaxf(((float)p0 + 0.5f) * 0.5f - 0.5f, 0.f);
    float h1 = fmaxf(((float)p1 + 0.5f) * 0.5f - 0.5f, 0.f);
    slo = (int)h0;
    shi = min((int)h1 + 1, srcH - 1);
}

// B-plane rows needed for dst rows [dlo,dhi] at resolution H.
__device__ __forceinline__ void bRange(int dlo, int dhi, int H, int& lo, int& hi) {
    float sc = 14.f / (float)H;
    int p0 = max(dlo - 1, 0), p1 = min(dhi + 1, H - 1);
    float f0 = clampf(((float)p0 + 0.5f) * sc - 0.5f, 0.f, 13.f);
    float f1 = clampf(((float)p1 + 0.5f) * sc - 0.5f, 0.f, 13.f);
    lo = (int)f0;
    hi = min((int)f1 + 1, 13);
}

__global__ __launch_bounds__(1024, 1)
void refiner_kernel(const float* __restrict__ x, const float* __restrict__ fv,
                    const float* __restrict__ conv_w, const float* __restrict__ conv_b,
                    const float* __restrict__ bng, const float* __restrict__ bnb,
                    const float* __restrict__ bnm, const float* __restrict__ bnv,
                    const float* __restrict__ W_w, const float* __restrict__ W_b,
                    float* __restrict__ out) {
    // persistent LDS
    __shared__ float sB[4 * 9 * 196];    // 28224 B (only cone rows written/read)
    __shared__ float y4loc[3 * 112];     // 1344 B
    __shared__ float hrow[2 * 224];      // 1792 B
    __shared__ int   pixOff[288];        // fv element offset per cone pixel
    __shared__ int   pixSB[288];         // sB base offset per cone pixel
    // phase-overlaid LDS
    __shared__ union {
        struct { short cbf[24 * 64 * 8]; } ph1;                       // 24576 B
        struct { float y1s[196]; float y2s[784]; float y3s[3136]; } ph2; // 16464 B
        struct { float Wt[32 * 225]; } ph3;                           // 28800 B
    } ovl;

    int tid = threadIdx.x;
    int b = blockIdx.x;
    int wv = tid >> 6, lane = tid & 63;

    // ---- dependence cone of output rows 2b, 2b+1 ----
    int y4lo = max(b - 1, 0), y4hi = min(b + 1, 111);
    int r3lo, r3hi; srcRange(y4lo, y4hi, 56, r3lo, r3hi);
    int r2lo, r2hi; srcRange(r3lo, r3hi, 28, r2lo, r2hi);
    int r1lo, r1hi; srcRange(r2lo, r2hi, 14, r1lo, r1hi);

    int bl[4], bh[4];
    bl[0] = max(r1lo - 1, 0); bh[0] = min(r1hi + 1, 13);
    bRange(r2lo, r2hi, 28, bl[1], bh[1]);
    bRange(r3lo, r3hi, 56, bl[2], bh[2]);
    bRange(y4lo, y4hi, 112, bl[3], bh[3]);

    int start[4], n_p = 0;
#pragma unroll
    for (int s = 0; s < 4; ++s) { start[s] = n_p; n_p += (bh[s] - bl[s] + 1) * 14; }

    // ---- pixel tables ----
    if (tid < 288) {
        int p = tid, voff = 0, vsb = 0;
        if (p < n_p) {
            int s = (p >= start[1]) + (p >= start[2]) + (p >= start[3]);
            int loc = p - start[s];
            int u = bl[s] + loc / 14, v = loc % 14;
            voff = ((3 - s) * 197 + 1 + u * 14 + v) * 768;
            vsb  = s * 1764 + u * 14 + v;
        }
        pixOff[p] = voff; pixSB[p] = vsb;
    }

    // ---- pack conv_w into MFMA B-fragments (bf16) in LDS ----
    // B[k][n]: lane n=lane&15 (tap, >=9 -> 0), k = k0*32 + (lane>>4)*8 + j.
    for (int e = tid; e < 6144; e += 1024) {        // e = uint (short pair) index
        int j2 = (e * 2) & 7;
        int ln = (e * 2 >> 3) & 63;
        int k0 = (e * 2 >> 9);
        int n = ln & 15, quad = ln >> 4;
        unsigned lo = 0, hi = 0;
        if (n < 9) {
            int k = k0 * 32 + quad * 8 + j2;
            lo = f2bf(conv_w[(size_t)(1 + k) * 9 + n]);
            hi = f2bf(conv_w[(size_t)(2 + k) * 9 + n]);
        }
        ((unsigned*)ovl.ph1.cbf)[e] = lo | (hi << 16);
    }

    float cw[9];
#pragma unroll
    for (int t = 0; t < 9; ++t) cw[t] = conv_w[t];   // channel-0 (h) taps
    float bias = conv_b[0];
    float scale = bng[0] * rsqrtf(bnv[0] + BN_EPS);
    float shift = bnb[0] - bnm[0] * scale;
    __syncthreads();

    // ---- MFMA: B_cone[p][t] = sum_k fv[p][k] * conv_w[1+k][t] ----
    int n_tiles = (n_p + 15) >> 4;
    for (int mt = wv; mt < n_tiles; mt += 16) {
        int m0 = mt * 16;
        int quad = lane >> 4;
        int mp = min(m0 + (lane & 15), 287);
        const float* ap = fv + pixOff[mp] + quad * 8;
        f32x4 c = {0.f, 0.f, 0.f, 0.f};
#pragma unroll 4
        for (int k0 = 0; k0 < 24; ++k0) {
            float4 a0 = *(const float4*)(ap + k0 * 32);
            float4 a1 = *(const float4*)(ap + k0 * 32 + 4);
            bf16x8 af;
            af[0] = (short)f2bf(a0.x); af[1] = (short)f2bf(a0.y);
            af[2] = (short)f2bf(a0.z); af[3] = (short)f2bf(a0.w);
            af[4] = (short)f2bf(a1.x); af[5] = (short)f2bf(a1.y);
            af[6] = (short)f2bf(a1.z); af[7] = (short)f2bf(a1.w);
            bf16x8 bfr = *(const bf16x8*)&ovl.ph1.cbf[(k0 * 64 + lane) * 8];
            c = __builtin_amdgcn_mfma_f32_16x16x32_bf16(af, bfr, c, 0, 0, 0);
        }
        // D: col(lane&15)=tap, row=quad*4+reg = pixel-in-tile
        int t = lane & 15;
        if (t < 9) {
#pragma unroll
            for (int r = 0; r < 4; ++r) {
                int p = m0 + quad * 4 + r;
                if (p < n_p) sB[pixSB[p] + t * 196] = c[r];
            }
        }
    }
    __syncthreads();

    // ---- Stage 1 (14x14, h = x, integer B lookup) ----
    {
        int n = (r1hi - r1lo + 1) * 14;
        if (tid < n) {
            int i = r1lo + tid / 14, j = tid % 14;
            float acc = bias;
#pragma unroll
            for (int a = 0; a < 3; ++a) {
                int p = i + a - 1;
                if (p < 0 || p >= 14) continue;
#pragma unroll
                for (int bq = 0; bq < 3; ++bq) {
                    int q = j + bq - 1;
                    if (q < 0 || q >= 14) continue;
                    int t = a * 3 + bq;
                    acc += cw[t] * x[p * 14 + q] + sB[t * 196 + p * 14 + q];
                }
            }
            ovl.ph2.y1s[i * 14 + j] = fmaxf(acc, 0.f) * scale + shift;
        }
    }
    __syncthreads();

    // ---- Stage 2 (28x28) ----
    {
        int n = (r2hi - r2lo + 1) * 28;
        if (tid < n) {
            int i = r2lo + tid / 28, j = tid % 28;
            float acc = stage_pixel(i, j, 28, ovl.ph2.y1s, 14, sB + 1764, cw, bias);
            ovl.ph2.y2s[i * 28 + j] = fmaxf(acc, 0.f) * scale + shift;
        }
    }
    __syncthreads();

    // ---- Stage 3 (56x56) ----
    {
        int n = (r3hi - r3lo + 1) * 56;
        if (tid < n) {
            int i = r3lo + tid / 56, j = tid % 56;
            float acc = stage_pixel(i, j, 56, ovl.ph2.y2s, 28, sB + 2 * 1764, cw, bias);
            ovl.ph2.y3s[i * 56 + j] = fmaxf(acc, 0.f) * scale + shift;
        }
    }
    __syncthreads();

    // ---- Stage 4: rows y4lo..y4hi, slot rr = i-(b-1) ----
    {
        int n = (y4hi - y4lo + 1) * 112;
        if (tid < n) {
            int i = y4lo + tid / 112, j = tid % 112;
            float acc = stage_pixel(i, j, 112, ovl.ph2.y3s, 56, sB + 3 * 1764, cw, bias);
            y4loc[(i - (b - 1)) * 112 + j] = fmaxf(acc, 0.f) * scale + shift;
        }
    }
    __syncthreads();   // also retires ph2 before Wt overlay

    // ---- up2(y4) rows 2b, 2b+1 -> hrow ----
    if (tid < 448) {
        int rr = tid / 224, w = tid % 224;
        int r = 2 * b + rr;
        float hy = clampf(((float)r + 0.5f) * 0.5f - 0.5f, 0.f, 111.f);
        int yy0 = (int)hy; float fy = hy - (float)yy0; int yy1 = min(yy0 + 1, 111);
        float hx = clampf(((float)w + 0.5f) * 0.5f - 0.5f, 0.f, 111.f);
        int xx0 = (int)hx; float fx = hx - (float)xx0; int xx1 = min(xx0 + 1, 111);
        int s0 = yy0 - (b - 1), s1 = yy1 - (b - 1);
        hrow[rr * 224 + w] = (1.f - fy) * ((1.f - fx) * y4loc[s0 * 112 + xx0] + fx * y4loc[s0 * 112 + xx1])
                           + fy         * ((1.f - fx) * y4loc[s1 * 112 + xx0] + fx * y4loc[s1 * 112 + xx1]);
    }

    // ---- Linear(224,224) via 7 LDS-transposed W chunks + sigmoid ----
    float a0 = 0.f, a1 = 0.f;
    for (int c = 0; c < 7; ++c) {
        __syncthreads();                       // hrow ready (c=0) / prev chunk done
        for (int e = tid; e < 7168; e += 1024) {
            int o = e >> 5, wl = e & 31;       // coalesced read of W rows
            ovl.ph3.Wt[wl * 225 + o] = W_w[o * 224 + (c << 5) + wl];
        }
        __syncthreads();
        if (tid < 224) {
#pragma unroll 8
            for (int wl = 0; wl < 32; ++wl) {
                float wvv = ovl.ph3.Wt[wl * 225 + tid];
                a0 += hrow[(c << 5) + wl] * wvv;
                a1 += hrow[224 + (c << 5) + wl] * wvv;
            }
        }
    }
    if (tid < 224) {
        float v0 = a0 + W_b[tid], v1 = a1 + W_b[tid];
        out[(size_t)(2 * b) * 224 + tid]     = 1.f / (1.f + expf(-v0));
        out[(size_t)(2 * b + 1) * 224 + tid] = 1.f / (1.f + expf(-v1));
    }
}

extern "C" void kernel_launch(void* const* d_in, const int* in_sizes, int n_in,
                              void* d_out, int out_size, void* d_ws, size_t ws_size,
                              hipStream_t stream) {
    (void)in_sizes; (void)n_in; (void)out_size; (void)d_ws; (void)ws_size;
    const float* x      = (const float*)d_in[0];
    const float* fv     = (const float*)d_in[1];
    const float* conv_w = (const float*)d_in[2];
    const float* conv_b = (const float*)d_in[3];
    const float* bng    = (const float*)d_in[4];
    const float* bnb    = (const float*)d_in[5];
    const float* bnm    = (const float*)d_in[6];
    const float* bnv    = (const float*)d_in[7];
    const float* W_w    = (const float*)d_in[8];
    const float* W_b    = (const float*)d_in[9];
    float* out = (float*)d_out;

    refiner_kernel<<<112, 1024, 0, stream>>>(x, fv, conv_w, conv_b,
                                             bng, bnb, bnm, bnv, W_w, W_b, out);
}

// Round 7
// 104.377 us; speedup vs baseline: 1.0882x; 1.0882x over previous
//
#include <hip/hip_runtime.h>
#include <math.h>

// ---------------------------------------------------------------------------
// Two-kernel Refiner (R7).
//
// Algebra: feature channels enter each stage linearly through bilinear
// resize -> pre-reduce B[s][t][u][v] = sum_c conv_w[1+c][t]*f14[s][c][u][v].
// NEW (R7): kernel A also pre-samples B in x at each stage's resolution:
//   Bt[s][t][u][q] = lerp_x(B[s][t][u][:], fx_s(q)),  widths {14,28,56,112}
// so kernel B's per-tap feature term is a 2-read y-lerp (same float ops as
// the 4-read bilinear -> bit-identical results). Stage 1 is the identity
// case (fx(q)=q exactly). BN is affine => commutes with upsample, so the
// h-upsample fuses into the consumer's sampling (unchanged).
//
// Kernel A: 56 blocks = (stage s, row u). Dot mapping (pixel p, k-slice,
// tap t): lanes with same (p,slice) broadcast the fv read; consecutive taps
// read consecutive conv_w floats. Then x-presample + write gBt. Also folds
// the final-layer up2-x into gWTf (R5, verified).
// Kernel B: 112 blocks; cone-pruned stages with WINDOWED LDS buffers
// (~850 floats of y-state), cone-only Bt load, D-row dots + up2-y lerp
// + bias + sigmoid (R5 structure).
//
// R6 lesson: per-block B recompute = 41x redundancy -> >= 6 us/CU of L2
// ingest even if coalesced. Zero-redundancy producer kernel is cheaper than
// any barrier (R3) or redundant-recompute (R6) single-kernel scheme.
// ---------------------------------------------------------------------------

#define BN_EPS 1e-5f

__device__ __forceinline__ float clampf(float x, float lo, float hi) {
    return fminf(fmaxf(x, lo), hi);
}

// src rows needed for dst rows [dlo,dhi] of a stage at H=2*srcH.
__device__ __forceinline__ void srcRange(int dlo, int dhi, int srcH, int& slo, int& shi) {
    int H = 2 * srcH;
    int p0 = max(dlo - 1, 0), p1 = min(dhi + 1, H - 1);
    float h0 = fmaxf(((float)p0 + 0.5f) * 0.5f - 0.5f, 0.f);
    float h1 = fmaxf(((float)p1 + 0.5f) * 0.5f - 0.5f, 0.f);
    slo = (int)h0;
    shi = min((int)h1 + 1, srcH - 1);
}

// B-plane rows needed for dst rows [dlo,dhi] at resolution H.
__device__ __forceinline__ void bRange(int dlo, int dhi, int H, int& lo, int& hi) {
    float sc = 14.f / (float)H;
    int p0 = max(dlo - 1, 0), p1 = min(dhi + 1, H - 1);
    float f0 = clampf(((float)p0 + 0.5f) * sc - 0.5f, 0.f, 13.f);
    float f1 = clampf(((float)p1 + 0.5f) * sc - 0.5f, 0.f, 13.f);
    lo = (int)f0;
    hi = min((int)f1 + 1, 13);
}

// gBt stage bases (floats) and widths
__constant__ int kW[4] = {14, 28, 56, 112};
__constant__ int kG[4] = {0, 1764, 5292, 12348};   // 9*14*cumsum(W)

// ---- Kernel A: B pre-reduction + x-presample + folded up2-x weights ----
__global__ __launch_bounds__(1024)
void compute_B_kernel(const float* __restrict__ fv, const float* __restrict__ conv_w,
                      const float* __restrict__ W_w,
                      float* __restrict__ gBt, float* __restrict__ gWTf) {
    __shared__ float part[1008];   // (p*9+t)*8 + slice
    __shared__ float sbrow[126];   // p*9+t

    int b = blockIdx.x;            // 0..55
    int s = b / 14, u = b % 14;
    int tid = threadIdx.x;

    // folded final-layer weights (R5, verified): 56 blocks x 448 == 25088
    if (tid < 448) {
        int idx = b * 448 + tid;
        int o = idx % 224, xx = idx / 224;
        float acc = 0.f;
#pragma unroll
        for (int d = -1; d <= 2; ++d) {
            int w = 2 * xx + d;
            if (w < 0 || w > 223) continue;
            float hx = clampf(((float)w + 0.5f) * 0.5f - 0.5f, 0.f, 111.f);
            int xx0 = (int)hx; float fx = hx - (float)xx0; int xx1 = min(xx0 + 1, 111);
            float c = (xx0 == xx ? 1.f - fx : 0.f) + (xx1 == xx ? fx : 0.f);
            acc += c * W_w[o * 224 + w];
        }
        gWTf[xx * 224 + o] = acc;
    }

    // dot: thread = (pixel p, k-slice sl, tap t); 14*8*9 = 1008
    if (tid < 1008) {
        int p = tid / 72, r = tid % 72;
        int sl = r / 9, t = r % 9;
        const float* fvrow = fv + ((size_t)(3 - s) * 197 + 1 + u * 14 + p) * 768 + sl * 96;
        const float* cwp = conv_w + (size_t)(1 + sl * 96) * 9 + t;
        float acc = 0.f;
#pragma unroll 32
        for (int m = 0; m < 96; ++m)
            acc += fvrow[m] * cwp[m * 9];
        part[(p * 9 + t) * 8 + sl] = acc;
    }
    __syncthreads();

    if (tid < 126) {
        float v = 0.f;
        int base = tid * 8;
#pragma unroll
        for (int k = 0; k < 8; ++k) v += part[base + k];
        sbrow[tid] = v;            // sbrow[p*9+t]
    }
    __syncthreads();

    // x-presample at this stage's resolution; s==0 degenerates to identity.
    int W = kW[s], G = kG[s];
    int n = 9 * W;
    if (tid < n) {
        int t = tid / W, q = tid % W;
        float sc = 14.f / (float)W;
        float fx = clampf(((float)q + 0.5f) * sc - 0.5f, 0.f, 13.f);
        int x0 = (int)fx; float f = fx - (float)x0; int x1 = min(x0 + 1, 13);
        float val = (1.f - f) * sbrow[x0 * 9 + t] + f * sbrow[x1 * 9 + t];
        gBt[G + (t * 14 + u) * W + q] = val;
    }
}

// Conv accumulator (pre-ReLU/BN) at pixel (i,j), resolution H, using
// x-presampled cone B-planes (cB, nr rows from bLo) and windowed h rows
// (hsrc, full width srcW==srcH, rows from srcLo).
__device__ __forceinline__ float stage_px(int i, int j, int H, int srcH,
                                          const float* __restrict__ hsrc, int srcLo,
                                          const float* __restrict__ cB, int nr, int bLo,
                                          const float* __restrict__ cw, float bias) {
    float featScale = 14.f / (float)H;
    float srcMax = (float)(srcH - 1);
    float acc = bias;
#pragma unroll
    for (int a = 0; a < 3; ++a) {
        int p = i + a - 1;
        if (p < 0 || p >= H) continue;                 // SAME zero padding
        float fy = clampf(((float)p + 0.5f) * featScale - 0.5f, 0.f, 13.f);
        int by0 = (int)fy; float byf = fy - (float)by0; int by1 = min(by0 + 1, 13);
        const float* b0 = cB + (by0 - bLo) * H;
        const float* b1 = cB + (by1 - bLo) * H;
        float hy = clampf(((float)p + 0.5f) * 0.5f - 0.5f, 0.f, srcMax);
        int hy0 = (int)hy; float fhy = hy - (float)hy0; int hy1 = min(hy0 + 1, srcH - 1);
        const float* h0 = hsrc + (hy0 - srcLo) * srcH;
        const float* h1 = hsrc + (hy1 - srcLo) * srcH;
#pragma unroll
        for (int bq = 0; bq < 3; ++bq) {
            int q = j + bq - 1;
            if (q < 0 || q >= H) continue;
            int t = a * 3 + bq;
            int toff = t * nr * H;
            float bv = (1.f - byf) * b0[toff + q] + byf * b1[toff + q];
            float hx = clampf(((float)q + 0.5f) * 0.5f - 0.5f, 0.f, srcMax);
            int hx0 = (int)hx; float fhx = hx - (float)hx0; int hx1 = min(hx0 + 1, srcH - 1);
            float hval = (1.f - fhy) * ((1.f - fhx) * h0[hx0] + fhx * h0[hx1])
                       + fhy         * ((1.f - fhx) * h1[hx0] + fhx * h1[hx1]);
            acc += cw[t] * hval + bv;
        }
    }
    return acc;
}

// ---- Kernel B: cone stages (windowed LDS) + D-dots + up2-y + sigmoid ----
__global__ __launch_bounds__(1024, 1)
void refine_kernel(const float* __restrict__ x,
                   const float* __restrict__ conv_w, const float* __restrict__ conv_b,
                   const float* __restrict__ bng, const float* __restrict__ bnb,
                   const float* __restrict__ bnm, const float* __restrict__ bnv,
                   const float* __restrict__ W_b,
                   const float* __restrict__ gBt, const float* __restrict__ gWTf,
                   float* __restrict__ out) {
    __shared__ float cB0[9 * 9 * 14];    // caps: nr0<=9, nr1<=7, nr2<=5, nr3<=4
    __shared__ float cB1[9 * 7 * 28];
    __shared__ float cB2[9 * 5 * 56];
    __shared__ float cB3[9 * 4 * 112];
    __shared__ float y1w[9 * 14];
    __shared__ float y2w[7 * 28];
    __shared__ float y3w[6 * 56];
    __shared__ float y4loc[3 * 112];
    __shared__ float partial[12 * 224];

    int tid = threadIdx.x;
    int b = blockIdx.x;

    // dependence cone of output rows 2b, 2b+1
    int y4lo = max(b - 1, 0), y4hi = min(b + 1, 111);
    int r3lo, r3hi; srcRange(y4lo, y4hi, 56, r3lo, r3hi);
    int r2lo, r2hi; srcRange(r3lo, r3hi, 28, r2lo, r2hi);
    int r1lo, r1hi; srcRange(r2lo, r2hi, 14, r1lo, r1hi);

    int bl0 = max(r1lo - 1, 0), bh0 = min(r1hi + 1, 13);
    int bl1, bh1; bRange(r2lo, r2hi, 28, bl1, bh1);
    int bl2, bh2; bRange(r3lo, r3hi, 56, bl2, bh2);
    int bl3, bh3; bRange(y4lo, y4hi, 112, bl3, bh3);
    int nr0 = min(bh0 - bl0 + 1, 9);
    int nr1 = min(bh1 - bl1 + 1, 7);
    int nr2 = min(bh2 - bl2 + 1, 5);
    int nr3 = min(bh3 - bl3 + 1, 4);

    // cone-only loads of x-presampled B (per-tap contiguous row windows)
    {
        int m = nr0 * 14, n = 9 * m, base = kG[0] + bl0 * 14;
        for (int e = tid; e < n; e += 1024) { int t = e / m; cB0[e] = gBt[base + t * 196 + (e - t * m)]; }
    }
    {
        int m = nr1 * 28, n = 9 * m, base = kG[1] + bl1 * 28;
        for (int e = tid; e < n; e += 1024) { int t = e / m; cB1[e] = gBt[base + t * 392 + (e - t * m)]; }
    }
    {
        int m = nr2 * 56, n = 9 * m, base = kG[2] + bl2 * 56;
        for (int e = tid; e < n; e += 1024) { int t = e / m; cB2[e] = gBt[base + t * 784 + (e - t * m)]; }
    }
    {
        int m = nr3 * 112, n = 9 * m, base = kG[3] + bl3 * 112;
        for (int e = tid; e < n; e += 1024) { int t = e / m; cB3[e] = gBt[base + t * 1568 + (e - t * m)]; }
    }

    float cw[9];
#pragma unroll
    for (int t = 0; t < 9; ++t) cw[t] = conv_w[t];
    float bias = conv_b[0];
    float scale = bng[0] * rsqrtf(bnv[0] + BN_EPS);
    float shift = bnb[0] - bnm[0] * scale;
    __syncthreads();

    // Stage 1 (14x14, h = x, B at integer coords -> direct lookup)
    {
        int n = (r1hi - r1lo + 1) * 14;
        if (tid < n) {
            int i = r1lo + tid / 14, j = tid % 14;
            float acc = bias;
#pragma unroll
            for (int a = 0; a < 3; ++a) {
                int p = i + a - 1;
                if (p < 0 || p >= 14) continue;
#pragma unroll
                for (int bq = 0; bq < 3; ++bq) {
                    int q = j + bq - 1;
                    if (q < 0 || q >= 14) continue;
                    int t = a * 3 + bq;
                    acc += cw[t] * x[p * 14 + q] + cB0[(t * nr0 + (p - bl0)) * 14 + q];
                }
            }
            y1w[(i - r1lo) * 14 + j] = fmaxf(acc, 0.f) * scale + shift;
        }
    }
    __syncthreads();

    // Stage 2 (28x28)
    {
        int n = (r2hi - r2lo + 1) * 28;
        if (tid < n) {
            int i = r2lo + tid / 28, j = tid % 28;
            float acc = stage_px(i, j, 28, 14, y1w, r1lo, cB1, nr1, bl1, cw, bias);
            y2w[(i - r2lo) * 28 + j] = fmaxf(acc, 0.f) * scale + shift;
        }
    }
    __syncthreads();

    // Stage 3 (56x56)
    {
        int n = (r3hi - r3lo + 1) * 56;
        if (tid < n) {
            int i = r3lo + tid / 56, j = tid % 56;
            float acc = stage_px(i, j, 56, 28, y2w, r2lo, cB2, nr2, bl2, cw, bias);
            y3w[(i - r3lo) * 56 + j] = fmaxf(acc, 0.f) * scale + shift;
        }
    }
    __syncthreads();

    // Stage 4: rows y4lo..y4hi, slot = i - y4lo
    {
        int n = (y4hi - y4lo + 1) * 112;
        if (tid < n) {
            int i = y4lo + tid / 112, j = tid % 112;
            float acc = stage_px(i, j, 112, 56, y3w, r3lo, cB3, nr3, bl3, cw, bias);
            y4loc[(i - y4lo) * 112 + j] = fmaxf(acc, 0.f) * scale + shift;
        }
    }
    __syncthreads();

    // D-row dots: D[slot][o] = sum_k y4loc[slot][k] * gWTf[k][o], K in 4 parts.
    // Slots beyond the row window produce garbage partials that are never read.
    if (tid < 896) {
        int kq = tid / 224, o = tid % 224;
        int k0 = kq * 28;
        float a0 = 0.f, a1 = 0.f, a2 = 0.f;
        for (int k = k0; k < k0 + 28; ++k) {
            float wf = gWTf[k * 224 + o];      // coalesced across o
            a0 += y4loc[k] * wf;
            a1 += y4loc[112 + k] * wf;
            a2 += y4loc[224 + k] * wf;
        }
        partial[(0 * 4 + kq) * 224 + o] = a0;
        partial[(1 * 4 + kq) * 224 + o] = a1;
        partial[(2 * 4 + kq) * 224 + o] = a2;
    }
    __syncthreads();

    // up2-y lerp of D rows + bias + sigmoid
    if (tid < 448) {
        int rr = tid / 224, o = tid % 224;
        int r = 2 * b + rr;
        float hy = clampf(((float)r + 0.5f) * 0.5f - 0.5f, 0.f, 111.f);
        int yy0 = (int)hy; float fy = hy - (float)yy0; int yy1 = min(yy0 + 1, 111);
        int s0 = yy0 - y4lo, s1 = yy1 - y4lo;
        float D0 = partial[(s0 * 4 + 0) * 224 + o] + partial[(s0 * 4 + 1) * 224 + o]
                 + partial[(s0 * 4 + 2) * 224 + o] + partial[(s0 * 4 + 3) * 224 + o];
        float D1 = partial[(s1 * 4 + 0) * 224 + o] + partial[(s1 * 4 + 1) * 224 + o]
                 + partial[(s1 * 4 + 2) * 224 + o] + partial[(s1 * 4 + 3) * 224 + o];
        float v = (1.f - fy) * D0 + fy * D1 + W_b[o];
        out[(size_t)r * 224 + o] = 1.f / (1.f + expf(-v));
    }
}

extern "C" void kernel_launch(void* const* d_in, const int* in_sizes, int n_in,
                              void* d_out, int out_size, void* d_ws, size_t ws_size,
                              hipStream_t stream) {
    (void)in_sizes; (void)n_in; (void)out_size; (void)ws_size;
    const float* x      = (const float*)d_in[0];
    const float* fv     = (const float*)d_in[1];
    const float* conv_w = (const float*)d_in[2];
    const float* conv_b = (const float*)d_in[3];
    const float* bng    = (const float*)d_in[4];
    const float* bnb    = (const float*)d_in[5];
    const float* bnm    = (const float*)d_in[6];
    const float* bnv    = (const float*)d_in[7];
    const float* W_w    = (const float*)d_in[8];
    const float* W_b    = (const float*)d_in[9];
    float* out = (float*)d_out;

    float* ws   = (float*)d_ws;
    float* gBt  = ws;              // 26460 floats (x-presampled B, 4 stages)
    float* gWTf = ws + 26460;      // 25088 floats (112 x 224 folded weights)

    compute_B_kernel<<<56, 1024, 0, stream>>>(fv, conv_w, W_w, gBt, gWTf);
    refine_kernel<<<112, 1024, 0, stream>>>(x, conv_w, conv_b, bng, bnb, bnm, bnv,
                                            W_b, gBt, gWTf, out);
}

// Round 8
// 87.533 us; speedup vs baseline: 1.2977x; 1.1924x over previous
//
#include <hip/hip_runtime.h>
#include <math.h>

// ---------------------------------------------------------------------------
// Two-kernel Refiner (R8).
//
// Algebra: feature channels enter each stage linearly through bilinear
// resize -> pre-reduce B[s][t][u][v] = sum_c conv_w[1+c][t]*f14[s][c][u][v].
// Kernel A also pre-samples B in x at each stage's resolution:
//   Bt[s][t][u][q] = lerp_x(B[s][t][u][:], fx_s(q)),  widths {14,28,56,112}
// so kernel B's per-tap feature term is a 2-read y-lerp (bit-identical to
// the 4-read bilinear). BN is affine => commutes with upsample, so the
// h-upsample fuses into the consumer's sampling. Final-layer up2-x is folded
// into gWTf; up2-y is a lerp of per-y4-row dot products.
//
// R8 (fixes R7's kernel-A L1-transaction pathology):
//  - conv_w staged once per block into LDS transposed [t][k] (row stride 776)
//    -> dot-phase LDS reads are lane-consecutive, conflict-free; global reads
//    of conv_w are one coalesced 6912-float sweep.
//  - one pixel per wave (14 waves): fv reads are coalesced 64-float chunks;
//    butterfly-reduce 9 accumulators.
//  - gWTf fold remapped (4 o's/block, xx across lanes) -> stride-2 reads.
// R6/R7 lessons: price loads in cachelines/instruction; redundant per-block
// recompute costs per-CU L2 ingest (~6 us) regardless of FLOPs.
// ---------------------------------------------------------------------------

#define BN_EPS 1e-5f

__device__ __forceinline__ float clampf(float x, float lo, float hi) {
    return fminf(fmaxf(x, lo), hi);
}

// src rows needed for dst rows [dlo,dhi] of a stage at H=2*srcH.
__device__ __forceinline__ void srcRange(int dlo, int dhi, int srcH, int& slo, int& shi) {
    int H = 2 * srcH;
    int p0 = max(dlo - 1, 0), p1 = min(dhi + 1, H - 1);
    float h0 = fmaxf(((float)p0 + 0.5f) * 0.5f - 0.5f, 0.f);
    float h1 = fmaxf(((float)p1 + 0.5f) * 0.5f - 0.5f, 0.f);
    slo = (int)h0;
    shi = min((int)h1 + 1, srcH - 1);
}

// B-plane rows needed for dst rows [dlo,dhi] at resolution H.
__device__ __forceinline__ void bRange(int dlo, int dhi, int H, int& lo, int& hi) {
    float sc = 14.f / (float)H;
    int p0 = max(dlo - 1, 0), p1 = min(dhi + 1, H - 1);
    float f0 = clampf(((float)p0 + 0.5f) * sc - 0.5f, 0.f, 13.f);
    float f1 = clampf(((float)p1 + 0.5f) * sc - 0.5f, 0.f, 13.f);
    lo = (int)f0;
    hi = min((int)f1 + 1, 13);
}

// gBt stage widths and bases (floats)
__constant__ int kW[4] = {14, 28, 56, 112};
__constant__ int kG[4] = {0, 1764, 5292, 12348};   // 9*14*cumsum(W)

// ---- Kernel A: B pre-reduction + x-presample + folded up2-x weights ----
__global__ __launch_bounds__(1024)
void compute_B_kernel(const float* __restrict__ fv, const float* __restrict__ conv_w,
                      const float* __restrict__ W_w,
                      float* __restrict__ gBt, float* __restrict__ gWTf) {
    __shared__ float sWc[9 * 776];   // conv_w channels 1..768, [t][k], pad 776
    __shared__ float sbrow[126];     // [v*9+t] for this (s,u) row

    int b = blockIdx.x;              // 0..55 = (stage s, row u)
    int s = b / 14, u = b % 14;
    int tid = threadIdx.x;
    int wv = tid >> 6, lane = tid & 63;

    // conv_w rows 1..768 -> LDS transposed (coalesced read of 6912 floats)
    for (int e = tid; e < 6912; e += 1024) {
        int k = e / 9, t = e - k * 9;
        sWc[t * 776 + k] = conv_w[9 + e];
    }

    // folded final-layer weights: 56 blocks x (4 o's x 112 xx) == 224x112.
    // W_w reads are stride-2 within an o-group (~14 cachelines/group).
    if (tid < 448) {
        int o = b * 4 + tid / 112, xx = tid % 112;
        float acc = 0.f;
#pragma unroll
        for (int d = -1; d <= 2; ++d) {
            int w = 2 * xx + d;
            if (w < 0 || w > 223) continue;
            float hx = clampf(((float)w + 0.5f) * 0.5f - 0.5f, 0.f, 111.f);
            int xx0 = (int)hx; float fx = hx - (float)xx0; int xx1 = min(xx0 + 1, 111);
            float c = (xx0 == xx ? 1.f - fx : 0.f) + (xx1 == xx ? fx : 0.f);
            acc += c * W_w[o * 224 + w];
        }
        gWTf[xx * 224 + o] = acc;
    }
    __syncthreads();

    // one pixel (u, v=wv) per wave: coalesced fv chunks, conflict-free LDS
    if (wv < 14) {
        const float* fvrow = fv + ((size_t)(3 - s) * 197 + 1 + u * 14 + wv) * 768;
        float acc[9];
#pragma unroll
        for (int t = 0; t < 9; ++t) acc[t] = 0.f;
#pragma unroll 3
        for (int m = 0; m < 12; ++m) {
            float v = fvrow[lane + 64 * m];
            const float* wp = sWc + lane + 64 * m;
#pragma unroll
            for (int t = 0; t < 9; ++t) acc[t] += v * wp[t * 776];
        }
#pragma unroll
        for (int t = 0; t < 9; ++t) {
#pragma unroll
            for (int off = 32; off > 0; off >>= 1)
                acc[t] += __shfl_down(acc[t], off, 64);
        }
        if (lane == 0) {
#pragma unroll
            for (int t = 0; t < 9; ++t) sbrow[wv * 9 + t] = acc[t];
        }
    }
    __syncthreads();

    // x-presample at this stage's resolution; s==0 degenerates to identity.
    int W = kW[s], G = kG[s];
    int n = 9 * W;
    if (tid < n) {
        int t = tid / W, q = tid - t * W;
        float sc = 14.f / (float)W;
        float fx = clampf(((float)q + 0.5f) * sc - 0.5f, 0.f, 13.f);
        int x0 = (int)fx; float f = fx - (float)x0; int x1 = min(x0 + 1, 13);
        float val = (1.f - f) * sbrow[x0 * 9 + t] + f * sbrow[x1 * 9 + t];
        gBt[G + (t * 14 + u) * W + q] = val;
    }
}

// Conv accumulator (pre-ReLU/BN) at pixel (i,j), resolution H, using
// x-presampled cone B-planes (cB, nr rows from bLo) and windowed h rows.
__device__ __forceinline__ float stage_px(int i, int j, int H, int srcH,
                                          const float* __restrict__ hsrc, int srcLo,
                                          const float* __restrict__ cB, int nr, int bLo,
                                          const float* __restrict__ cw, float bias) {
    float featScale = 14.f / (float)H;
    float srcMax = (float)(srcH - 1);
    float acc = bias;
#pragma unroll
    for (int a = 0; a < 3; ++a) {
        int p = i + a - 1;
        if (p < 0 || p >= H) continue;                 // SAME zero padding
        float fy = clampf(((float)p + 0.5f) * featScale - 0.5f, 0.f, 13.f);
        int by0 = (int)fy; float byf = fy - (float)by0; int by1 = min(by0 + 1, 13);
        const float* b0 = cB + (by0 - bLo) * H;
        const float* b1 = cB + (by1 - bLo) * H;
        float hy = clampf(((float)p + 0.5f) * 0.5f - 0.5f, 0.f, srcMax);
        int hy0 = (int)hy; float fhy = hy - (float)hy0; int hy1 = min(hy0 + 1, srcH - 1);
        const float* h0 = hsrc + (hy0 - srcLo) * srcH;
        const float* h1 = hsrc + (hy1 - srcLo) * srcH;
#pragma unroll
        for (int bq = 0; bq < 3; ++bq) {
            int q = j + bq - 1;
            if (q < 0 || q >= H) continue;
            int t = a * 3 + bq;
            int toff = t * nr * H;
            float bv = (1.f - byf) * b0[toff + q] + byf * b1[toff + q];
            float hx = clampf(((float)q + 0.5f) * 0.5f - 0.5f, 0.f, srcMax);
            int hx0 = (int)hx; float fhx = hx - (float)hx0; int hx1 = min(hx0 + 1, srcH - 1);
            float hval = (1.f - fhy) * ((1.f - fhx) * h0[hx0] + fhx * h0[hx1])
                       + fhy         * ((1.f - fhx) * h1[hx0] + fhx * h1[hx1]);
            acc += cw[t] * hval + bv;
        }
    }
    return acc;
}

// ---- Kernel B: cone stages (windowed LDS) + D-dots + up2-y + sigmoid ----
__global__ __launch_bounds__(1024, 1)
void refine_kernel(const float* __restrict__ x,
                   const float* __restrict__ conv_w, const float* __restrict__ conv_b,
                   const float* __restrict__ bng, const float* __restrict__ bnb,
                   const float* __restrict__ bnm, const float* __restrict__ bnv,
                   const float* __restrict__ W_b,
                   const float* __restrict__ gBt, const float* __restrict__ gWTf,
                   float* __restrict__ out) {
    __shared__ float cB0[9 * 9 * 14];    // caps: nr0<=9, nr1<=7, nr2<=5, nr3<=4
    __shared__ float cB1[9 * 7 * 28];
    __shared__ float cB2[9 * 5 * 56];
    __shared__ float cB3[9 * 4 * 112];
    __shared__ float y1w[9 * 14];
    __shared__ float y2w[7 * 28];
    __shared__ float y3w[6 * 56];
    __shared__ float y4loc[3 * 112];
    __shared__ float partial[12 * 224];

    int tid = threadIdx.x;
    int b = blockIdx.x;

    // dependence cone of output rows 2b, 2b+1
    int y4lo = max(b - 1, 0), y4hi = min(b + 1, 111);
    int r3lo, r3hi; srcRange(y4lo, y4hi, 56, r3lo, r3hi);
    int r2lo, r2hi; srcRange(r3lo, r3hi, 28, r2lo, r2hi);
    int r1lo, r1hi; srcRange(r2lo, r2hi, 14, r1lo, r1hi);

    int bl0 = max(r1lo - 1, 0), bh0 = min(r1hi + 1, 13);
    int bl1, bh1; bRange(r2lo, r2hi, 28, bl1, bh1);
    int bl2, bh2; bRange(r3lo, r3hi, 56, bl2, bh2);
    int bl3, bh3; bRange(y4lo, y4hi, 112, bl3, bh3);
    int nr0 = min(bh0 - bl0 + 1, 9);
    int nr1 = min(bh1 - bl1 + 1, 7);
    int nr2 = min(bh2 - bl2 + 1, 5);
    int nr3 = min(bh3 - bl3 + 1, 4);

    // cone-only loads of x-presampled B (per-tap contiguous row windows,
    // single predicated round per tap -- no runtime division)
    {
        int m = nr0 * 14, base = kG[0] + bl0 * 14;
#pragma unroll
        for (int t = 0; t < 9; ++t)
            if (tid < m) cB0[t * m + tid] = gBt[base + t * 196 + tid];
    }
    {
        int m = nr1 * 28, base = kG[1] + bl1 * 28;
#pragma unroll
        for (int t = 0; t < 9; ++t)
            if (tid < m) cB1[t * m + tid] = gBt[base + t * 392 + tid];
    }
    {
        int m = nr2 * 56, base = kG[2] + bl2 * 56;
#pragma unroll
        for (int t = 0; t < 9; ++t)
            if (tid < m) cB2[t * m + tid] = gBt[base + t * 784 + tid];
    }
    {
        int m = nr3 * 112, base = kG[3] + bl3 * 112;
#pragma unroll
        for (int t = 0; t < 9; ++t)
            if (tid < m) cB3[t * m + tid] = gBt[base + t * 1568 + tid];
    }

    float cw[9];
#pragma unroll
    for (int t = 0; t < 9; ++t) cw[t] = conv_w[t];
    float bias = conv_b[0];
    float scale = bng[0] * rsqrtf(bnv[0] + BN_EPS);
    float shift = bnb[0] - bnm[0] * scale;
    __syncthreads();

    // Stage 1 (14x14, h = x, B at integer coords -> direct lookup)
    {
        int n = (r1hi - r1lo + 1) * 14;
        if (tid < n) {
            int i = r1lo + tid / 14, j = tid % 14;
            float acc = bias;
#pragma unroll
            for (int a = 0; a < 3; ++a) {
                int p = i + a - 1;
                if (p < 0 || p >= 14) continue;
#pragma unroll
                for (int bq = 0; bq < 3; ++bq) {
                    int q = j + bq - 1;
                    if (q < 0 || q >= 14) continue;
                    int t = a * 3 + bq;
                    acc += cw[t] * x[p * 14 + q] + cB0[(t * nr0 + (p - bl0)) * 14 + q];
                }
            }
            y1w[(i - r1lo) * 14 + j] = fmaxf(acc, 0.f) * scale + shift;
        }
    }
    __syncthreads();

    // Stage 2 (28x28)
    {
        int n = (r2hi - r2lo + 1) * 28;
        if (tid < n) {
            int i = r2lo + tid / 28, j = tid % 28;
            float acc = stage_px(i, j, 28, 14, y1w, r1lo, cB1, nr1, bl1, cw, bias);
            y2w[(i - r2lo) * 28 + j] = fmaxf(acc, 0.f) * scale + shift;
        }
    }
    __syncthreads();

    // Stage 3 (56x56)
    {
        int n = (r3hi - r3lo + 1) * 56;
        if (tid < n) {
            int i = r3lo + tid / 56, j = tid % 56;
            float acc = stage_px(i, j, 56, 28, y2w, r2lo, cB2, nr2, bl2, cw, bias);
            y3w[(i - r3lo) * 56 + j] = fmaxf(acc, 0.f) * scale + shift;
        }
    }
    __syncthreads();

    // Stage 4: rows y4lo..y4hi, slot = i - y4lo
    {
        int n = (y4hi - y4lo + 1) * 112;
        if (tid < n) {
            int i = y4lo + tid / 112, j = tid % 112;
            float acc = stage_px(i, j, 112, 56, y3w, r3lo, cB3, nr3, bl3, cw, bias);
            y4loc[(i - y4lo) * 112 + j] = fmaxf(acc, 0.f) * scale + shift;
        }
    }
    __syncthreads();

    // D-row dots: D[slot][o] = sum_k y4loc[slot][k] * gWTf[k][o], K in 4 parts.
    if (tid < 896) {
        int kq = tid / 224, o = tid % 224;
        int k0 = kq * 28;
        float a0 = 0.f, a1 = 0.f, a2 = 0.f;
        for (int k = k0; k < k0 + 28; ++k) {
            float wf = gWTf[k * 224 + o];      // coalesced across o
            a0 += y4loc[k] * wf;
            a1 += y4loc[112 + k] * wf;
            a2 += y4loc[224 + k] * wf;
        }
        partial[(0 * 4 + kq) * 224 + o] = a0;
        partial[(1 * 4 + kq) * 224 + o] = a1;
        partial[(2 * 4 + kq) * 224 + o] = a2;
    }
    __syncthreads();

    // up2-y lerp of D rows + bias + sigmoid
    if (tid < 448) {
        int rr = tid / 224, o = tid % 224;
        int r = 2 * b + rr;
        float hy = clampf(((float)r + 0.5f) * 0.5f - 0.5f, 0.f, 111.f);
        int yy0 = (int)hy; float fy = hy - (float)yy0; int yy1 = min(yy0 + 1, 111);
        int s0 = yy0 - y4lo, s1 = yy1 - y4lo;
        float D0 = partial[(s0 * 4 + 0) * 224 + o] + partial[(s0 * 4 + 1) * 224 + o]
                 + partial[(s0 * 4 + 2) * 224 + o] + partial[(s0 * 4 + 3) * 224 + o];
        float D1 = partial[(s1 * 4 + 0) * 224 + o] + partial[(s1 * 4 + 1) * 224 + o]
                 + partial[(s1 * 4 + 2) * 224 + o] + partial[(s1 * 4 + 3) * 224 + o];
        float v = (1.f - fy) * D0 + fy * D1 + W_b[o];
        out[(size_t)r * 224 + o] = 1.f / (1.f + expf(-v));
    }
}

extern "C" void kernel_launch(void* const* d_in, const int* in_sizes, int n_in,
                              void* d_out, int out_size, void* d_ws, size_t ws_size,
                              hipStream_t stream) {
    (void)in_sizes; (void)n_in; (void)out_size; (void)ws_size;
    const float* x      = (const float*)d_in[0];
    const float* fv     = (const float*)d_in[1];
    const float* conv_w = (const float*)d_in[2];
    const float* conv_b = (const float*)d_in[3];
    const float* bng    = (const float*)d_in[4];
    const float* bnb    = (const float*)d_in[5];
    const float* bnm    = (const float*)d_in[6];
    const float* bnv    = (const float*)d_in[7];
    const float* W_w    = (const float*)d_in[8];
    const float* W_b    = (const float*)d_in[9];
    float* out = (float*)d_out;

    float* ws   = (float*)d_ws;
    float* gBt  = ws;              // 26460 floats (x-presampled B, 4 stages)
    float* gWTf = ws + 26460;      // 25088 floats (112 x 224 folded weights)

    compute_B_kernel<<<56, 1024, 0, stream>>>(fv, conv_w, W_w, gBt, gWTf);
    refine_kernel<<<112, 1024, 0, stream>>>(x, conv_w, conv_b, bng, bnb, bnm, bnv,
                                            W_b, gBt, gWTf, out);
}